// Round 5
// baseline (392.722 us; speedup 1.0000x reference)
//
#include <hip/hip_runtime.h>
#include <stdint.h>

#define ROWLEN 4096
#define KSEL   1024
#define NTHREADS 256
#define NBINS  2048      // 11-bit digit = v >> 21
#define KEYCAP 1536      // < 1024 above-boundary + <=512 boundary group
#define GLCAP  256
typedef unsigned long long u64;

// Monotonic float->uint map: order(f) preserved as unsigned compare.
__device__ __forceinline__ uint32_t f2u_sortable(float f) {
    uint32_t u = __float_as_uint(f);
    return u ^ ((int32_t)u < 0 ? 0xFFFFFFFFu : 0x80000000u);
}

__device__ __forceinline__ void cmpex(u64 &a, u64 &b, bool maxFirst) {
    u64 lo = a < b ? a : b;
    u64 hi = a < b ? b : a;
    a = maxFirst ? hi : lo;
    b = maxFirst ? lo : hi;
}

// Full descending bitonic sort of P=2^LOGP keys held by one wave,
// element i = lane + 64*e. j<64 via shfl_xor, j>=64 in-register. No LDS.
template<int LOGP>
__device__ __forceinline__ void wave_bitonic_desc(u64 r[], int lane) {
    constexpr int P = 1 << LOGP;
    constexpr int E = (P > 64) ? (P / 64) : 1;
#pragma unroll
    for (int k = 2; k <= P; k <<= 1) {
#pragma unroll
        for (int j = k >> 1; j > 0; j >>= 1) {
            if (j >= 64) {
                const int jr = j >> 6;
#pragma unroll
                for (int e = 0; e < E; ++e) {
                    if ((e & jr) == 0) {
                        int il = lane + 64 * e;
                        cmpex(r[e], r[e | jr], (il & k) == 0);
                    }
                }
            } else {
#pragma unroll
                for (int e = 0; e < E; ++e) {
                    u64 o = __shfl_xor(r[e], j, 64);
                    int i = lane + 64 * e;
                    bool takeMax = (((i & j) == 0) == ((i & k) == 0));
                    r[e] = ((r[e] > o) == takeMax) ? r[e] : o;   // keys distinct
                }
            }
        }
    }
}

__global__ __launch_bounds__(NTHREADS, 8) void adaptive_topk_kernel(
    const float* __restrict__ in, int* __restrict__ out_idx, int* __restrict__ out_k)
{
    __shared__ uint32_t A32[NBINS / 2];   // packed u16 bins: hist -> suffix-excl -> cursors
    __shared__ u64 keys[KEYCAP];          // 12 KB grouped scatter buffer
    __shared__ uint32_t glist[GLCAP];     // (n<<16)|base per active group
    __shared__ uint32_t wavetot[4];
    __shared__ float wsum[4], wsum2[4];
    __shared__ int sh_d1, sh_ng, sh_gp, sh_fb;

    const int row  = blockIdx.x;
    const int tid  = threadIdx.x;
    const int lane = tid & 63;
    const int wv   = tid >> 6;
    const float* __restrict__ rowp = in + (size_t)row * ROWLEN;
    int* __restrict__ orow = out_idx + (size_t)row * KSEL;

    const uint4 z0 = {0u, 0u, 0u, 0u};
    ((uint4*)A32)[tid] = z0;              // clear 1024 words = 2048 u16 bins
    if (tid == 0) { sh_ng = 0; sh_gp = 0; sh_fb = 0; }
    __syncthreads();

    // ---- load row into REGISTERS + 11-bit histogram (packed u16) + moments ----
    uint4 w[4];                            // elem idx = 4*(tid + 256*it) + e
    float s = 0.0f, s2 = 0.0f;
    const float4* r4 = (const float4*)rowp;
#pragma unroll
    for (int it = 0; it < 4; ++it) {
        float4 v = r4[tid + 256 * it];
        s += (v.x + v.y) + (v.z + v.w);
        s2 = fmaf(v.x, v.x, fmaf(v.y, v.y, fmaf(v.z, v.z, fmaf(v.w, v.w, s2))));
        uint32_t ux = f2u_sortable(v.x), uy = f2u_sortable(v.y);
        uint32_t uz = f2u_sortable(v.z), uw = f2u_sortable(v.w);
        w[it].x = ux; w[it].y = uy; w[it].z = uz; w[it].w = uw;
        uint32_t bx = ux >> 21, by = uy >> 21, bz = uz >> 21, bw = uw >> 21;
        atomicAdd(&A32[bx >> 1], (bx & 1) ? (1u << 16) : 1u);
        atomicAdd(&A32[by >> 1], (by & 1) ? (1u << 16) : 1u);
        atomicAdd(&A32[bz >> 1], (bz & 1) ? (1u << 16) : 1u);
        atomicAdd(&A32[bw >> 1], (bw & 1) ? (1u << 16) : 1u);
    }
    for (int off = 32; off > 0; off >>= 1) {
        s  += __shfl_down(s, off);
        s2 += __shfl_down(s2, off);
    }
    if (lane == 0) { wsum[wv] = s; wsum2[wv] = s2; }
    __syncthreads();                      // hist + wsum complete
    if (tid == 0) {
        double S  = (double)wsum[0] + wsum[1] + wsum[2] + wsum[3];
        double S2 = (double)wsum2[0] + wsum2[1] + wsum2[2] + wsum2[3];
        double var = (S2 - S * S / (double)ROWLEN) / (double)(ROWLEN - 1);
        float sp = log1pf(expf((float)var));
        float ka = 512.0f * (1.0f + 0.1f * sp);
        ka = fminf(fmaxf(ka, 128.0f), 1024.0f);
        out_k[row] = (int)ka;
    }

    // ---- in-place EXCLUSIVE suffix scan over bins (A[g] := #elems in bins > g),
    //      fused with boundary-digit detection ----
    uint4 hw = ((uint4*)A32)[tid];        // my 8 bins (4 words)
    uint32_t cnt[8] = { hw.x & 0xFFFFu, hw.x >> 16, hw.y & 0xFFFFu, hw.y >> 16,
                        hw.z & 0xFFFFu, hw.z >> 16, hw.w & 0xFFFFu, hw.w >> 16 };
    uint32_t csum = 0;
#pragma unroll
    for (int b = 0; b < 8; ++b) csum += cnt[b];
    uint32_t incl = csum;                 // inclusive suffix over chunk sums in wave
#pragma unroll
    for (int off = 1; off < 64; off <<= 1) {
        uint32_t t = __shfl_down(incl, off);
        if (lane + off < 64) incl += t;
    }
    if (lane == 0) wavetot[wv] = incl;
    __syncthreads();
    uint32_t later = 0;
    for (int w2 = wv + 1; w2 < 4; ++w2) later += wavetot[w2];
    uint32_t run = (incl - csum) + later; // elems in bins after my chunk
    uint32_t runs[8];
#pragma unroll
    for (int b = 7; b >= 0; --b) {
        uint32_t h = cnt[b];
        if (run < KSEL && KSEL <= run + h) sh_d1 = 8 * tid + b;
        runs[b] = run;                    // exclusive suffix for bin 8*tid+b
        run += h;
    }
    uint4 ww;
    ww.x = runs[0] | (runs[1] << 16);
    ww.y = runs[2] | (runs[3] << 16);
    ww.z = runs[4] | (runs[5] << 16);
    ww.w = runs[6] | (runs[7] << 16);
    ((uint4*)A32)[tid] = ww;
    __syncthreads();                      // A = bases, sh_d1 visible

    const int d1 = sh_d1;

    // ---- group list build (from regs) + grouped scatter (cursors = A halves) ----
#pragma unroll
    for (int b = 0; b < 8; ++b) {
        int g = 8 * tid + b;
        uint32_t n = cnt[b];
        if (g >= d1 && n > 0) {
            if (n > 512) sh_fb = 1;
            int p = atomicAdd(&sh_ng, 1);
            if (p < GLCAP) glist[p] = (n << 16) | runs[b];
            else sh_fb = 1;
        }
    }
#pragma unroll
    for (int it = 0; it < 4; ++it) {
        uint32_t vv[4] = { w[it].x, w[it].y, w[it].z, w[it].w };
#pragma unroll
        for (int e = 0; e < 4; ++e) {
            uint32_t u = vv[e];
            int g = (int)(u >> 21);
            if (g >= d1) {
                uint32_t old = atomicAdd(&A32[g >> 1], (g & 1) ? (1u << 16) : 1u);
                uint32_t pos = (g & 1) ? (old >> 16) : (old & 0xFFFFu);
                int idx = 4 * (tid + 256 * it) + e;
                if (pos < KEYCAP)
                    keys[pos] = ((u64)u << 12) | (u64)(ROWLEN - 1 - idx);
            }
        }
    }
    __syncthreads();                      // keys + glist complete

    const int ng = min(sh_ng, GLCAP);
    if (!sh_fb) {
        // ---- per-group in-wave sorts (no barriers, dynamic load balance) ----
#define GROUP_SORT(LOGP, EE)                                                  \
        {                                                                     \
            u64 rr[EE];                                                       \
            _Pragma("unroll")                                                 \
            for (int e = 0; e < EE; ++e) {                                    \
                int i = lane + 64 * e;                                        \
                rr[e] = (i < n) ? keys[base + i] : 0ull;                      \
            }                                                                 \
            wave_bitonic_desc<LOGP>(rr, lane);                                \
            _Pragma("unroll")                                                 \
            for (int e = 0; e < EE; ++e) {                                    \
                int i = lane + 64 * e;                                        \
                if (i < quota)                                                \
                    orow[base + i] = (ROWLEN - 1) - (int)(rr[e] & 0xFFFu);    \
            }                                                                 \
        }
        for (;;) {
            int gi = 0;
            if (lane == 0) gi = atomicAdd(&sh_gp, 1);
            gi = __shfl(gi, 0);
            if (gi >= ng) break;
            uint32_t ent = glist[gi];
            int base  = (int)(ent & 0xFFFFu);
            int n     = (int)(ent >> 16);
            int quota = min(n, KSEL - base);
            if (n <= 64)       GROUP_SORT(6, 1)
            else if (n <= 128) GROUP_SORT(7, 2)
            else if (n <= 256) GROUP_SORT(8, 4)
            else               GROUP_SORT(9, 8)
        }
#undef GROUP_SORT
    } else if (tid < 64) {
        // ---- exact cooperative fallback (statistically never taken) ----
        u64 prev = ~0ull;
        for (int r = 0; r < KSEL; ++r) {
            u64 best = 0;
            for (int c = lane; c < ROWLEN; c += 64) {
                u64 K = ((u64)f2u_sortable(rowp[c]) << 12) | (u64)(ROWLEN - 1 - c);
                if (K < prev && K > best) best = K;
            }
            for (int off = 32; off > 0; off >>= 1) {
                u64 o = __shfl_xor(best, off, 64);
                best = best > o ? best : o;
            }
            if (lane == 0) orow[r] = (ROWLEN - 1) - (int)(best & 0xFFFu);
            prev = best;
        }
    }
}

extern "C" void kernel_launch(void* const* d_in, const int* in_sizes, int n_in,
                              void* d_out, int out_size, void* d_ws, size_t ws_size,
                              hipStream_t stream) {
    const float* in = (const float*)d_in[0];
    const int B = in_sizes[0] / (ROWLEN * ROWLEN);   // 4
    const int nrows = B * ROWLEN;                    // 16384
    int* out = (int*)d_out;
    int* out_idx = out;                              // B*L*KSEL
    int* out_k   = out + (size_t)nrows * KSEL;       // B*L
    adaptive_topk_kernel<<<dim3(nrows), dim3(NTHREADS), 0, stream>>>(in, out_idx, out_k);
}